// Round 15
// baseline (1383.903 us; speedup 1.0000x reference)
//
#include <hip/hip_runtime.h>

// LSTMTrafficPredictor: fused 2-layer LSTM + FC head via MFMA (bf16 hi/lo split).
// B=2048, T=512, IN=4, H1=64, H2=32, FC=16, OUT=1.
// R15: config audit showed R11..R14 ran grid=256 = ONE block/CU (occupancy 23%
// = the single block's 8 waves): the per-step block-wide barrier had no overlap
// partner -> ~1340 cyc/step stall (R14: issue 1285 of 2623 cyc). Fix: halve the
// block, double the grid: BLK=256 (4 waves), MB=4, grid=512 -> TRUE 2 blocks/CU.
// Per-CU: 16 batches/step (2x), same LDS reads/CU, same trans/lane; block A's
// barrier drain overlaps block B's issue.
// Registers (the known killer): per wave L1 4 tiles (96 AGPR) + L2 2 tiles (48)
// + bb2 (8) = 152 AGPR pinned + ~100 VGPR = 252 <= 256 @ bounds(256,2).
// WRITE_SIZE is the spill tripwire; if it balloons, revert to R14.
// Carried structure: unroll-2 ping-pong, 1 barrier/step, AGPR-pinned frags,
// redistributed activations (now ACT2 too), pairwise-shared rcp, exact-x k-map.
// k-map (K=128): [h1(0..63) | x(64..67) | bias-one(68) | pad | h2(96..127)]
//   L1: 4 tiles/wave (unit w*16+nt*4+quad, acc[rg]=gate rg), ks 0..2
//   L2: 2 tiles/wave (unit w*8+nt*4+quad,  acc[rg]=gate rg), ks {0,1,3}
//   z offset(k,n) = (k>>5)*512 + (((k>>3)&3)*16+n)*8 + (k&7); frag read = lane*8.

#define T_LEN 512
#define IN_F  4
#define H1    64
#define H2    32
#define FCN   16
#define MB    4
#define BLK   256

typedef __attribute__((ext_vector_type(8))) short s8b;  // 8 bf16 = 4 VGPR
typedef __attribute__((ext_vector_type(4))) float f4;   // MFMA acc
typedef __attribute__((ext_vector_type(4))) int   i4;   // 4 dwords (pin unit)

union S8U { s8b v; i4 d; unsigned short u[8]; };
union F4U { f4 v; i4 d; float f[4]; };

// Pin 4 consecutive regs into AGPRs; asm def kills rematerialization.
#define APIN4(x) asm volatile("" : "+a"((x).d))

__device__ __forceinline__ float rcp_(float x) { return __builtin_amdgcn_rcpf(x); }
__device__ __forceinline__ float tanh_(float x) { return 1.0f - 2.0f * rcp_(__expf(2.0f * x) + 1.0f); }

__device__ __forceinline__ unsigned short bf16_rne(float f) {
    unsigned u = __float_as_uint(f);
    u = u + 0x7FFFu + ((u >> 16) & 1u);
    return (unsigned short)(u >> 16);
}
__device__ __forceinline__ float bf16_f(unsigned short h) {
    return __uint_as_float(((unsigned)h) << 16);
}

// ---- step-body macros (P = read buffer, NP = write buffer, compile-time) ----
#define STEP_MFMA(P)                                                            \
    f4 a1A[4] = {{0,0,0,0},{0,0,0,0},{0,0,0,0},{0,0,0,0}};                      \
    f4 a1B[4] = {{0,0,0,0},{0,0,0,0},{0,0,0,0},{0,0,0,0}};                      \
    f4 ac2a[2] = {bb2[0].v, bb2[1].v}, ac2b[2] = {{0,0,0,0},{0,0,0,0}};         \
    _Pragma("unroll")                                                           \
    for (int ks = 0; ks < 4; ++ks) {                                            \
        const s8b zh = *(const s8b*)(&zz[P][0][0] + ks * 512 + offF);           \
        const s8b zl = *(const s8b*)(&zz[P][1][0] + ks * 512 + offF);           \
        if (ks < 3) {                                                           \
            _Pragma("unroll")                                                   \
            for (int nt = 0; nt < 4; ++nt) {                                    \
                a1A[nt] = __builtin_amdgcn_mfma_f32_16x16x32_bf16(wf1h[nt][ks].v, zh, a1A[nt], 0, 0, 0); \
                a1B[nt] = __builtin_amdgcn_mfma_f32_16x16x32_bf16(wf1h[nt][ks].v, zl, a1B[nt], 0, 0, 0); \
                a1B[nt] = __builtin_amdgcn_mfma_f32_16x16x32_bf16(wf1l[nt][ks].v, zh, a1B[nt], 0, 0, 0); \
            }                                                                   \
        }                                                                       \
        if (ks != 2) {                                                          \
            const int kf = (ks < 2) ? ks : 2;                                   \
            _Pragma("unroll")                                                   \
            for (int nt = 0; nt < 2; ++nt) {                                    \
                ac2a[nt] = __builtin_amdgcn_mfma_f32_16x16x32_bf16(wf2h[nt][kf].v, zh, ac2a[nt], 0, 0, 0); \
                ac2b[nt] = __builtin_amdgcn_mfma_f32_16x16x32_bf16(wf2h[nt][kf].v, zl, ac2b[nt], 0, 0, 0); \
                ac2b[nt] = __builtin_amdgcn_mfma_f32_16x16x32_bf16(wf2l[nt][kf].v, zh, ac2b[nt], 0, 0, 0); \
            }                                                                   \
        }                                                                       \
    }

// L1 activations redistributed: owner lanes (col<4) publish 4 summed gate-f4s;
// every lane then owns ONE (unit,batch) set. Same-wave LDS -> no barrier.
#define STEP_ACT1(NP)                                                           \
    {                                                                           \
        if (col < MB) {                                                         \
            _Pragma("unroll")                                                   \
            for (int nt = 0; nt < 4; ++nt)                                      \
                *(f4*)&gsc[w][nt * 16 + quad * 4 + col][0] = a1A[nt] + a1B[nt]; \
        }                                                                       \
        const f4 g = *(const f4*)&gsc[w][lane][0];                              \
        const float dI = 1.0f + __expf(-g[0]);                                  \
        const float dF = 1.0f + __expf(-g[1]);                                  \
        const float rIF = rcp_(dI * dF);                                        \
        const float I = dF * rIF, F = dI * rIF;                                 \
        const float dG = __expf(2.0f * g[2]) + 1.0f;                            \
        const float dO = 1.0f + __expf(-g[3]);                                  \
        const float rGO = rcp_(dG * dO);                                        \
        const float G = 1.0f - 2.0f * (dO * rGO), O = dG * rGO;                 \
        c1 = fmaf(F, c1, I * G);                                                \
        const float h = O * tanh_(c1);                                          \
        const unsigned short hh = bf16_rne(h);                                  \
        zz[NP][0][offH] = hh;                                                   \
        zz[NP][1][offH] = bf16_rne(h - bf16_f(hh));                             \
    }

// L2 activations redistributed: owners publish 2 summed gate-f4s; lanes<32 own one set.
#define STEP_ACT2(NP)                                                           \
    {                                                                           \
        if (col < MB) {                                                         \
            *(f4*)&gs2[w][quad * 4 + col][0]      = ac2a[0] + ac2b[0];          \
            *(f4*)&gs2[w][16 + quad * 4 + col][0] = ac2a[1] + ac2b[1];          \
        }                                                                       \
        if (lane < 32) {                                                        \
            const f4 g = *(const f4*)&gs2[w][lane][0];                          \
            const float dI = 1.0f + __expf(-g[0]);                              \
            const float dF = 1.0f + __expf(-g[1]);                              \
            const float rIF = rcp_(dI * dF);                                    \
            const float I = dF * rIF, F = dI * rIF;                             \
            const float dG = __expf(2.0f * g[2]) + 1.0f;                        \
            const float dO = 1.0f + __expf(-g[3]);                              \
            const float rGO = rcp_(dG * dO);                                    \
            const float G = 1.0f - 2.0f * (dO * rGO), O = dG * rGO;             \
            c2 = fmaf(F, c2, I * G);                                            \
            const float h = O * tanh_(c2);                                      \
            const unsigned short hh = bf16_rne(h);                              \
            zz[NP][0][off2r] = hh;                                              \
            zz[NP][1][off2r] = bf16_rne(h - bf16_f(hh));                        \
        }                                                                       \
    }

__global__ __launch_bounds__(BLK, 2)
void lstm_mfma(const float* __restrict__ x,
               const float* __restrict__ Wih1, const float* __restrict__ Whh1,
               const float* __restrict__ bih1, const float* __restrict__ bhh1,
               const float* __restrict__ Wih2, const float* __restrict__ Whh2,
               const float* __restrict__ bih2, const float* __restrict__ bhh2,
               const float* __restrict__ fc1_w, const float* __restrict__ fc1_b,
               const float* __restrict__ fc2_w, const float* __restrict__ fc2_b,
               float* __restrict__ out)
{
    __shared__ __align__(16) unsigned short zz[2][2][2048];  // 16 KB
    __shared__ __align__(16) float gsc[4][64][4];            // 4 KB L1 scratch
    __shared__ __align__(16) float gs2[4][32][4];            // 2 KB L2 scratch
    __shared__ __align__(16) float h2f[MB * H2];
    __shared__ __align__(16) float fcs[MB * FCN];

    const int t    = threadIdx.x;
    const int lane = t & 63;
    const int w    = t >> 6;      // wave 0..3
    const int col  = lane & 15;   // batch col (valid < MB) / A-frag row
    const int quad = lane >> 4;
    const int b0   = blockIdx.x * MB;

    // ---- weight fragments (gate-complete interleaved mapping) ----
    S8U wf1h[4][3], wf1l[4][3];   // layer1: 4 tiles x ks 0..2   (96 AGPR)
    S8U wf2h[2][3], wf2l[2][3];   // layer2: 2 tiles x ks {0,1,3} (48 AGPR)
    #pragma unroll
    for (int nt = 0; nt < 4; ++nt) {
        const int r1 = (col & 3) * 64 + w * 16 + nt * 4 + (col >> 2);
        #pragma unroll
        for (int ks = 0; ks < 3; ++ks) {
            #pragma unroll
            for (int j = 0; j < 8; ++j) {
                const int k = ks * 32 + quad * 8 + j;
                float wv;
                if      (k < H1)      wv = Whh1[r1 * H1 + k];
                else if (k < H1 + 4)  wv = Wih1[r1 * IN_F + (k - H1)];
                else if (k == 68)     wv = bih1[r1] + bhh1[r1];   // bias col
                else                  wv = 0.f;
                const unsigned short hh = bf16_rne(wv);
                wf1h[nt][ks].u[j] = hh;
                wf1l[nt][ks].u[j] = bf16_rne(wv - bf16_f(hh));
            }
        }
    }
    #pragma unroll
    for (int nt = 0; nt < 2; ++nt) {
        const int r2 = (col & 3) * 32 + w * 8 + nt * 4 + (col >> 2);
        #pragma unroll
        for (int kf = 0; kf < 3; ++kf) {
            #pragma unroll
            for (int j = 0; j < 8; ++j) {
                const int k = ((kf < 2) ? kf * 32 : 96) + quad * 8 + j;
                const float wv = (k < H1) ? Wih2[r2 * H1 + k]
                                          : Whh2[r2 * H2 + (k - 96)];
                const unsigned short hh = bf16_rne(wv);
                wf2h[nt][kf].u[j] = hh;
                wf2l[nt][kf].u[j] = bf16_rne(wv - bf16_f(hh));
            }
        }
    }
    // layer2 biases as MFMA C-init (tile nt unit u2 = w*8+nt*4+quad)
    F4U bb2[2];
    #pragma unroll
    for (int nt = 0; nt < 2; ++nt) {
        const int u2 = w * 8 + nt * 4 + quad;
        bb2[nt].f[0] = bih2[u2]      + bhh2[u2];
        bb2[nt].f[1] = bih2[32 + u2] + bhh2[32 + u2];
        bb2[nt].f[2] = bih2[64 + u2] + bhh2[64 + u2];
        bb2[nt].f[3] = bih2[96 + u2] + bhh2[96 + u2];
    }

    // ---- PIN fragments + bias into AGPRs ----
    #pragma unroll
    for (int nt = 0; nt < 4; ++nt)
        #pragma unroll
        for (int ks = 0; ks < 3; ++ks) { APIN4(wf1h[nt][ks]); APIN4(wf1l[nt][ks]); }
    #pragma unroll
    for (int nt = 0; nt < 2; ++nt)
        #pragma unroll
        for (int kf = 0; kf < 3; ++kf) { APIN4(wf2h[nt][kf]); APIN4(wf2l[nt][kf]); }
    APIN4(bb2[0]); APIN4(bb2[1]);

    // ---- init LDS: zero z; bias-one col (both pp); x(0) ----
    {
        int* pz = (int*)zz;
        #pragma unroll
        for (int i = 0; i < 16; ++i) pz[t + i * BLK] = 0;
    }
    __syncthreads();
    if (t < 16) {                           // off(k=68,n) = 1024 + n*8 + 4
        zz[0][0][1024 + t * 8 + 4] = 0x3F80;
        zz[1][0][1024 + t * 8 + 4] = 0x3F80;
    }
    if (t < MB * IN_F) {                    // x(0) at k=64+f: off = 1024 + n*8 + f
        const int n = t >> 2, f = t & 3;
        const float xv = x[(size_t)(b0 + n) * T_LEN * IN_F + f];
        const unsigned short xh = bf16_rne(xv);
        zz[0][0][1024 + n * 8 + f] = xh;
        zz[0][1][1024 + n * 8 + f] = bf16_rne(xv - bf16_f(xh));
    }
    float c1 = 0.f;   // L1 redistributed: unit w*16+(lane>>4)*4+((lane>>2)&3), batch lane&3
    float c2 = 0.f;   // L2 redistributed (lane<32): unit w*8+(lane>>4)*4+((lane>>2)&3), batch lane&3

    // store offsets
    const int uH    = w * 16 + ((lane >> 4) << 2) + ((lane >> 2) & 3);
    const int nH    = lane & 3;
    const int offH  = (uH >> 5) * 512 + (((uH >> 3) & 3) * 16 + nH) * 8 + (uH & 7);
    const int u2r   = w * 8 + ((lane >> 4) << 2) + ((lane >> 2) & 3);   // lane<32
    const int off2r = 1536 + (((u2r >> 3) & 3) * 16 + nH) * 8 + (u2r & 7);
    const int offF  = lane * 8;                    // frag read base
    const int xn_   = (t >> 2) & 3, xf_ = t & 3;   // x-prefetch role (t < 16)
    const float* xp = x + (size_t)(b0 + xn_) * T_LEN * IN_F + IN_F + xf_;  // -> x(1)
    __syncthreads();

    // ================= main recurrence: unrolled x2, 1 barrier/step ==========
    #pragma unroll 1
    for (int s2 = 0; s2 < T_LEN / 2; ++s2) {
        // ---------- body A: s = 2*s2 (read zz[0], write zz[1]) ----------
        {
            float xn = 0.f;
            if (t < MB * IN_F) xn = *xp;           // x(2*s2+1), always valid
            STEP_MFMA(0)
            STEP_ACT1(1)
            if (s2 != 0) STEP_ACT2(1)              // gates2 belong to step s-1
            if (t < MB * IN_F) {
                const unsigned short xh = bf16_rne(xn);
                zz[1][0][1024 + xn_ * 8 + xf_] = xh;
                zz[1][1][1024 + xn_ * 8 + xf_] = bf16_rne(xn - bf16_f(xh));
            }
            xp += IN_F;
        }
        __syncthreads();
        // ---------- body B: s = 2*s2+1 (read zz[1], write zz[0]) ----------
        {
            float xn = 0.f;
            const bool ld = (t < MB * IN_F) && (s2 != T_LEN / 2 - 1);
            if (ld) xn = *xp;                      // x(2*s2+2)
            STEP_MFMA(1)
            STEP_ACT1(0)
            STEP_ACT2(0)                           // s >= 1 always here
            if (ld) {
                const unsigned short xh = bf16_rne(xn);
                zz[0][0][1024 + xn_ * 8 + xf_] = xh;
                zz[0][1][1024 + xn_ * 8 + xf_] = bf16_rne(xn - bf16_f(xh));
            }
            xp += IN_F;
        }
        __syncthreads();
    }

    // ================= epilogue: layer2 step T-1 (zz[0]: h1(511), h2(510)) ====
    {
        f4 ac2a[2] = {bb2[0].v, bb2[1].v}, ac2b[2] = {{0,0,0,0},{0,0,0,0}};
        #pragma unroll
        for (int kf = 0; kf < 3; ++kf) {
            const int zks = (kf < 2) ? kf : 3;
            const s8b zh = *(const s8b*)(&zz[0][0][0] + zks * 512 + offF);
            const s8b zl = *(const s8b*)(&zz[0][1][0] + zks * 512 + offF);
            #pragma unroll
            for (int nt = 0; nt < 2; ++nt) {
                ac2a[nt] = __builtin_amdgcn_mfma_f32_16x16x32_bf16(wf2h[nt][kf].v, zh, ac2a[nt], 0, 0, 0);
                ac2b[nt] = __builtin_amdgcn_mfma_f32_16x16x32_bf16(wf2h[nt][kf].v, zl, ac2b[nt], 0, 0, 0);
                ac2b[nt] = __builtin_amdgcn_mfma_f32_16x16x32_bf16(wf2l[nt][kf].v, zh, ac2b[nt], 0, 0, 0);
            }
        }
        if (col < MB) {
            *(f4*)&gs2[w][quad * 4 + col][0]      = ac2a[0] + ac2b[0];
            *(f4*)&gs2[w][16 + quad * 4 + col][0] = ac2a[1] + ac2b[1];
        }
        __syncthreads();
        if (lane < 32) {
            const f4 g = *(const f4*)&gs2[w][lane][0];
            const float dI = 1.0f + __expf(-g[0]);
            const float dF = 1.0f + __expf(-g[1]);
            const float rIF = rcp_(dI * dF);
            const float I = dF * rIF, F = dI * rIF;
            const float dG = __expf(2.0f * g[2]) + 1.0f;
            const float dO = 1.0f + __expf(-g[3]);
            const float rGO = rcp_(dG * dO);
            const float G = 1.0f - 2.0f * (dO * rGO), O = dG * rGO;
            c2 = fmaf(F, c2, I * G);
            h2f[nH * H2 + u2r] = O * tanh_(c2);
        }
    }
    __syncthreads();

    // ================= FC head =================
    if (t < MB * FCN) {
        const int b = t >> 4, j = t & 15;
        float s1 = fc1_b[j];
        #pragma unroll
        for (int k = 0; k < H2; ++k)
            s1 = fmaf(fc1_w[j * H2 + k], h2f[b * H2 + k], s1);
        fcs[b * FCN + j] = fmaxf(s1, 0.f);
    }
    __syncthreads();
    if (t < MB) {
        float s2v = fc2_b[0];
        #pragma unroll
        for (int j = 0; j < FCN; ++j)
            s2v = fmaf(fc2_w[j], fcs[t * FCN + j], s2v);
        out[b0 + t] = s2v;
    }
}

extern "C" void kernel_launch(void* const* d_in, const int* in_sizes, int n_in,
                              void* d_out, int out_size, void* d_ws, size_t ws_size,
                              hipStream_t stream) {
    const float* x     = (const float*)d_in[0];
    const float* Wih1  = (const float*)d_in[1];
    const float* Whh1  = (const float*)d_in[2];
    const float* bih1  = (const float*)d_in[3];
    const float* bhh1  = (const float*)d_in[4];
    const float* Wih2  = (const float*)d_in[5];
    const float* Whh2  = (const float*)d_in[6];
    const float* bih2  = (const float*)d_in[7];
    const float* bhh2  = (const float*)d_in[8];
    const float* fc1_w = (const float*)d_in[9];
    const float* fc1_b = (const float*)d_in[10];
    const float* fc2_w = (const float*)d_in[11];
    const float* fc2_b = (const float*)d_in[12];
    float* out = (float*)d_out;

    const int n_batch = 2048;
    dim3 grid(n_batch / MB), block(BLK);
    lstm_mfma<<<grid, block, 0, stream>>>(x, Wih1, Whh1, bih1, bhh1,
                                          Wih2, Whh2, bih2, bhh2,
                                          fc1_w, fc1_b, fc2_w, fc2_b, out);
}

// Round 16
// 614.293 us; speedup vs baseline: 2.2528x; 2.2528x over previous
//
#include <hip/hip_runtime.h>

// LSTMTrafficPredictor: fused 2-layer LSTM + FC head via MFMA (bf16 hi/lo split).
// B=2048, T=512, IN=4, H1=64, H2=32, FC=16, OUT=1.
// R16 = R14 (575us champion) + ACT2 redistribution (logic validated in R15,
// which failed only on register pressure: 152 pinned AGPR at BLK=256 spilled).
// CLOSED AXES (measured, do not revisit):
//  - multi-block/CU: >~80 pinned weight regs/wave forbids >2 waves/SIMD
//    (R10 spill @128-cap, R15 spill @BLK=256). R14's 1 block x 8 waves is the
//    only feasible point for 3-term compensation. Weights/wave halve only by
//    dropping the Wlo term (precision risk, not taken).
//  - MFMA count cuts (R12) and LDS-read cuts (R13): flat/regressed - not the
//    bottleneck. Combined pipe busy ~85% (MfmaUtil 36 + VALUBusy 49, disjoint).
// ACT2 redistribution: owner lanes (col<8) publish summed gate-f4s to gs2;
// lanes<32 each own ONE (unit,batch) set (wave64 op with upper half masked
// skips that half's issue pass). ACT2 VALU/trans issue halves.
// Config: MB=8, BLK=512, grid=256, bounds(512,2), AGPR-pinned frags,
// unroll-2 ping-pong, 1 barrier/step, redistributed ACT1+ACT2, paired rcp.
// k-map (K=128): [h1(0..63) | x(64..67) | bias-one(68) | pad | h2(96..127)]
//   L1: 2 tiles/wave (unit w*8+nt*4+quad, acc[rg]=gate rg), ks 0..2
//   L2: 1 tile/wave  (unit w*4+quad,      acc[rg]=gate rg), ks {0,1,3}
//   z offset(k,n) = (k>>5)*512 + (((k>>3)&3)*16+n)*8 + (k&7); frag read = lane*8.
// ACT1 ownership: lane -> unit w*8+(lane>>5)*4+((lane>>3)&3), batch lane&7.
// ACT2 ownership (lane<32): unit w*4+(lane>>3), batch lane&7.

#define T_LEN 512
#define IN_F  4
#define H1    64
#define H2    32
#define FCN   16
#define MB    8
#define BLK   512

typedef __attribute__((ext_vector_type(8))) short s8b;  // 8 bf16 = 4 VGPR
typedef __attribute__((ext_vector_type(4))) float f4;   // MFMA acc
typedef __attribute__((ext_vector_type(4))) int   i4;   // 4 dwords (pin unit)

union S8U { s8b v; i4 d; unsigned short u[8]; };
union F4U { f4 v; i4 d; float f[4]; };

// Pin 4 consecutive regs into AGPRs; asm def kills rematerialization.
#define APIN4(x) asm volatile("" : "+a"((x).d))

__device__ __forceinline__ float rcp_(float x) { return __builtin_amdgcn_rcpf(x); }
__device__ __forceinline__ float tanh_(float x) { return 1.0f - 2.0f * rcp_(__expf(2.0f * x) + 1.0f); }

__device__ __forceinline__ unsigned short bf16_rne(float f) {
    unsigned u = __float_as_uint(f);
    u = u + 0x7FFFu + ((u >> 16) & 1u);
    return (unsigned short)(u >> 16);
}
__device__ __forceinline__ float bf16_f(unsigned short h) {
    return __uint_as_float(((unsigned)h) << 16);
}

// ---- step-body macros (P = read buffer, NP = write buffer, compile-time) ----
#define STEP_MFMA(P)                                                            \
    f4 a1A[2] = {{0,0,0,0},{0,0,0,0}}, a1B[2] = {{0,0,0,0},{0,0,0,0}};          \
    f4 ac2a = bb2.v, ac2b = {0,0,0,0};                                          \
    _Pragma("unroll")                                                           \
    for (int ks = 0; ks < 4; ++ks) {                                            \
        const s8b zh = *(const s8b*)(&zz[P][0][0] + ks * 512 + offF);           \
        const s8b zl = *(const s8b*)(&zz[P][1][0] + ks * 512 + offF);           \
        if (ks < 3) {                                                           \
            _Pragma("unroll")                                                   \
            for (int nt = 0; nt < 2; ++nt) {                                    \
                a1A[nt] = __builtin_amdgcn_mfma_f32_16x16x32_bf16(wf1h[nt][ks].v, zh, a1A[nt], 0, 0, 0); \
                a1B[nt] = __builtin_amdgcn_mfma_f32_16x16x32_bf16(wf1h[nt][ks].v, zl, a1B[nt], 0, 0, 0); \
                a1B[nt] = __builtin_amdgcn_mfma_f32_16x16x32_bf16(wf1l[nt][ks].v, zh, a1B[nt], 0, 0, 0); \
            }                                                                   \
        }                                                                       \
        if (ks != 2) {                                                          \
            const int kf = (ks < 2) ? ks : 2;                                   \
            ac2a = __builtin_amdgcn_mfma_f32_16x16x32_bf16(wf2h[kf].v, zh, ac2a, 0, 0, 0); \
            ac2b = __builtin_amdgcn_mfma_f32_16x16x32_bf16(wf2h[kf].v, zl, ac2b, 0, 0, 0); \
            ac2b = __builtin_amdgcn_mfma_f32_16x16x32_bf16(wf2l[kf].v, zh, ac2b, 0, 0, 0); \
        }                                                                       \
    }

// L1 activations, redistributed: publish summed gates to wave scratch, then
// every lane processes ONE (unit,batch) set. Same-wave LDS -> no barrier.
#define STEP_ACT1(NP)                                                           \
    {                                                                           \
        if (col < MB) {                                                         \
            *(f4*)&gsc[w][quad * 8 + col][0]      = a1A[0] + a1B[0];            \
            *(f4*)&gsc[w][32 + quad * 8 + col][0] = a1A[1] + a1B[1];            \
        }                                                                       \
        const f4 g = *(const f4*)&gsc[w][lane][0];                              \
        const float dI = 1.0f + __expf(-g[0]);                                  \
        const float dF = 1.0f + __expf(-g[1]);                                  \
        const float rIF = rcp_(dI * dF);                                        \
        const float I = dF * rIF, F = dI * rIF;                                 \
        const float dG = __expf(2.0f * g[2]) + 1.0f;                            \
        const float dO = 1.0f + __expf(-g[3]);                                  \
        const float rGO = rcp_(dG * dO);                                        \
        const float G = 1.0f - 2.0f * (dO * rGO), O = dG * rGO;                 \
        c1 = fmaf(F, c1, I * G);                                                \
        const float h = O * tanh_(c1);                                          \
        const unsigned short hh = bf16_rne(h);                                  \
        zz[NP][0][offH] = hh;                                                   \
        zz[NP][1][offH] = bf16_rne(h - bf16_f(hh));                             \
    }

// L2 activations, redistributed: owners (col<8) publish one gate-f4; lanes<32
// each own ONE (unit,batch) set. Upper-half-masked wave ops skip a pass.
#define STEP_ACT2(NP)                                                           \
    {                                                                           \
        if (col < MB) *(f4*)&gs2[w][quad * 8 + col][0] = ac2a + ac2b;           \
        if (lane < 32) {                                                        \
            const f4 g = *(const f4*)&gs2[w][lane][0];                          \
            const float dI = 1.0f + __expf(-g[0]);                              \
            const float dF = 1.0f + __expf(-g[1]);                              \
            const float rIF = rcp_(dI * dF);                                    \
            const float I = dF * rIF, F = dI * rIF;                             \
            const float dG = __expf(2.0f * g[2]) + 1.0f;                        \
            const float dO = 1.0f + __expf(-g[3]);                              \
            const float rGO = rcp_(dG * dO);                                    \
            const float G = 1.0f - 2.0f * (dO * rGO), O = dG * rGO;             \
            c2 = fmaf(F, c2, I * G);                                            \
            const float h = O * tanh_(c2);                                      \
            const unsigned short hh = bf16_rne(h);                              \
            zz[NP][0][off2r] = hh;                                              \
            zz[NP][1][off2r] = bf16_rne(h - bf16_f(hh));                        \
        }                                                                       \
    }

__global__ __launch_bounds__(BLK, 2)
void lstm_mfma(const float* __restrict__ x,
               const float* __restrict__ Wih1, const float* __restrict__ Whh1,
               const float* __restrict__ bih1, const float* __restrict__ bhh1,
               const float* __restrict__ Wih2, const float* __restrict__ Whh2,
               const float* __restrict__ bih2, const float* __restrict__ bhh2,
               const float* __restrict__ fc1_w, const float* __restrict__ fc1_b,
               const float* __restrict__ fc2_w, const float* __restrict__ fc2_b,
               float* __restrict__ out)
{
    __shared__ __align__(16) unsigned short zz[2][2][2048];  // 16 KB
    __shared__ __align__(16) float gsc[8][64][4];            // 8 KB L1 scratch
    __shared__ __align__(16) float gs2[8][32][4];            // 4 KB L2 scratch
    __shared__ __align__(16) float h2f[MB * H2];
    __shared__ __align__(16) float fcs[MB * FCN];

    const int t    = threadIdx.x;
    const int lane = t & 63;
    const int w    = t >> 6;      // wave 0..7
    const int col  = lane & 15;   // batch col (valid < MB) / A-frag row
    const int quad = lane >> 4;
    const int b0   = blockIdx.x * MB;

    // ---- weight fragments (gate-complete interleaved mapping) ----
    S8U wf1h[2][3], wf1l[2][3];   // layer1: 2 tiles x ks 0..2
    S8U wf2h[3],    wf2l[3];      // layer2: 1 tile  x ks {0,1,3}
    #pragma unroll
    for (int nt = 0; nt < 2; ++nt) {
        const int r1 = (col & 3) * 64 + w * 8 + nt * 4 + (col >> 2);
        #pragma unroll
        for (int ks = 0; ks < 3; ++ks) {
            #pragma unroll
            for (int j = 0; j < 8; ++j) {
                const int k = ks * 32 + quad * 8 + j;
                float wv;
                if      (k < H1)      wv = Whh1[r1 * H1 + k];
                else if (k < H1 + 4)  wv = Wih1[r1 * IN_F + (k - H1)];
                else if (k == 68)     wv = bih1[r1] + bhh1[r1];   // bias col
                else                  wv = 0.f;
                const unsigned short hh = bf16_rne(wv);
                wf1h[nt][ks].u[j] = hh;
                wf1l[nt][ks].u[j] = bf16_rne(wv - bf16_f(hh));
            }
        }
    }
    {
        const int r2 = (col & 3) * 32 + w * 4 + (col >> 2);
        #pragma unroll
        for (int kf = 0; kf < 3; ++kf) {
            #pragma unroll
            for (int j = 0; j < 8; ++j) {
                const int k = ((kf < 2) ? kf * 32 : 96) + quad * 8 + j;
                const float wv = (k < H1) ? Wih2[r2 * H1 + k]
                                          : Whh2[r2 * H2 + (k - 96)];
                const unsigned short hh = bf16_rne(wv);
                wf2h[kf].u[j] = hh;
                wf2l[kf].u[j] = bf16_rne(wv - bf16_f(hh));
            }
        }
    }
    // layer2 biases as MFMA C-init vector (producer lane's unit u2 = w*4+quad)
    const int u2 = w * 4 + quad;
    F4U bb2;
    bb2.f[0] = bih2[u2]      + bhh2[u2];
    bb2.f[1] = bih2[32 + u2] + bhh2[32 + u2];
    bb2.f[2] = bih2[64 + u2] + bhh2[64 + u2];
    bb2.f[3] = bih2[96 + u2] + bhh2[96 + u2];

    // ---- PIN fragments + bias into AGPRs ----
    #pragma unroll
    for (int nt = 0; nt < 2; ++nt)
        #pragma unroll
        for (int ks = 0; ks < 3; ++ks) { APIN4(wf1h[nt][ks]); APIN4(wf1l[nt][ks]); }
    #pragma unroll
    for (int kf = 0; kf < 3; ++kf) { APIN4(wf2h[kf]); APIN4(wf2l[kf]); }
    APIN4(bb2);

    // ---- init LDS: zero z; bias-one col (both pp); x(0) ----
    {
        int* pz = (int*)zz;
        #pragma unroll
        for (int i = 0; i < 8; ++i) pz[t + i * BLK] = 0;
    }
    __syncthreads();
    if (t < 16) {                           // off(k=68,n) = 1024 + n*8 + 4
        zz[0][0][1024 + t * 8 + 4] = 0x3F80;
        zz[1][0][1024 + t * 8 + 4] = 0x3F80;
    }
    if (t < MB * IN_F) {                    // x(0) at k=64+f: off = 1024 + n*8 + f
        const int n = t >> 2, f = t & 3;
        const float xv = x[(size_t)(b0 + n) * T_LEN * IN_F + f];
        const unsigned short xh = bf16_rne(xv);
        zz[0][0][1024 + n * 8 + f] = xh;
        zz[0][1][1024 + n * 8 + f] = bf16_rne(xv - bf16_f(xh));
    }
    float c1 = 0.f;   // ACT1: unit w*8+(lane>>5)*4+((lane>>3)&3), batch lane&7
    float c2 = 0.f;   // ACT2 (lane<32): unit w*4+(lane>>3), batch lane&7

    // store offsets
    const int uH    = w * 8 + ((lane >> 5) << 2) + ((lane >> 3) & 3);
    const int nH    = lane & 7;
    const int offH  = (uH >> 5) * 512 + (((uH >> 3) & 3) * 16 + nH) * 8 + (uH & 7);
    const int u2r   = w * 4 + (lane >> 3);         // lane<32 ownership
    const int off2r = 1536 + (((u2r >> 3) & 3) * 16 + nH) * 8 + (u2r & 7);
    const int offF  = lane * 8;                    // frag read base
    const int xn_   = (t >> 2) & 7, xf_ = t & 3;   // x-prefetch role (t < 32)
    const float* xp = x + (size_t)(b0 + xn_) * T_LEN * IN_F + IN_F + xf_;  // -> x(1)
    __syncthreads();

    // ================= main recurrence: unrolled x2, 1 barrier/step ==========
    #pragma unroll 1
    for (int s2 = 0; s2 < T_LEN / 2; ++s2) {
        // ---------- body A: s = 2*s2 (read zz[0], write zz[1]) ----------
        {
            float xn = 0.f;
            if (t < MB * IN_F) xn = *xp;           // x(2*s2+1), always valid
            STEP_MFMA(0)
            STEP_ACT1(1)
            if (s2 != 0) STEP_ACT2(1)              // gates2 belong to step s-1
            if (t < MB * IN_F) {
                const unsigned short xh = bf16_rne(xn);
                zz[1][0][1024 + xn_ * 8 + xf_] = xh;
                zz[1][1][1024 + xn_ * 8 + xf_] = bf16_rne(xn - bf16_f(xh));
            }
            xp += IN_F;
        }
        __syncthreads();
        // ---------- body B: s = 2*s2+1 (read zz[1], write zz[0]) ----------
        {
            float xn = 0.f;
            const bool ld = (t < MB * IN_F) && (s2 != T_LEN / 2 - 1);
            if (ld) xn = *xp;                      // x(2*s2+2)
            STEP_MFMA(1)
            STEP_ACT1(0)
            STEP_ACT2(0)                           // s >= 1 always here
            if (ld) {
                const unsigned short xh = bf16_rne(xn);
                zz[0][0][1024 + xn_ * 8 + xf_] = xh;
                zz[0][1][1024 + xn_ * 8 + xf_] = bf16_rne(xn - bf16_f(xh));
            }
            xp += IN_F;
        }
        __syncthreads();
    }

    // ================= epilogue: layer2 step T-1 (zz[0]: h1(511), h2(510)) ====
    {
        f4 ac2a = bb2.v, ac2b = {0,0,0,0};
        #pragma unroll
        for (int kf = 0; kf < 3; ++kf) {
            const int zks = (kf < 2) ? kf : 3;
            const s8b zh = *(const s8b*)(&zz[0][0][0] + zks * 512 + offF);
            const s8b zl = *(const s8b*)(&zz[0][1][0] + zks * 512 + offF);
            ac2a = __builtin_amdgcn_mfma_f32_16x16x32_bf16(wf2h[kf].v, zh, ac2a, 0, 0, 0);
            ac2b = __builtin_amdgcn_mfma_f32_16x16x32_bf16(wf2h[kf].v, zl, ac2b, 0, 0, 0);
            ac2b = __builtin_amdgcn_mfma_f32_16x16x32_bf16(wf2l[kf].v, zh, ac2b, 0, 0, 0);
        }
        if (col < MB) *(f4*)&gs2[w][quad * 8 + col][0] = ac2a + ac2b;
        if (lane < 32) {
            const f4 g = *(const f4*)&gs2[w][lane][0];
            const float dI = 1.0f + __expf(-g[0]);
            const float dF = 1.0f + __expf(-g[1]);
            const float rIF = rcp_(dI * dF);
            const float I = dF * rIF, F = dI * rIF;
            const float dG = __expf(2.0f * g[2]) + 1.0f;
            const float dO = 1.0f + __expf(-g[3]);
            const float rGO = rcp_(dG * dO);
            const float G = 1.0f - 2.0f * (dO * rGO), O = dG * rGO;
            c2 = fmaf(F, c2, I * G);
            h2f[nH * H2 + u2r] = O * tanh_(c2);
        }
    }
    __syncthreads();

    // ================= FC head =================
    if (t < MB * FCN) {
        const int b = t >> 4, j = t & 15;
        float s1 = fc1_b[j];
        #pragma unroll
        for (int k = 0; k < H2; ++k)
            s1 = fmaf(fc1_w[j * H2 + k], h2f[b * H2 + k], s1);
        fcs[b * FCN + j] = fmaxf(s1, 0.f);
    }
    __syncthreads();
    if (t < MB) {
        float s2v = fc2_b[0];
        #pragma unroll
        for (int j = 0; j < FCN; ++j)
            s2v = fmaf(fc2_w[j], fcs[t * FCN + j], s2v);
        out[b0 + t] = s2v;
    }
}

extern "C" void kernel_launch(void* const* d_in, const int* in_sizes, int n_in,
                              void* d_out, int out_size, void* d_ws, size_t ws_size,
                              hipStream_t stream) {
    const float* x     = (const float*)d_in[0];
    const float* Wih1  = (const float*)d_in[1];
    const float* Whh1  = (const float*)d_in[2];
    const float* bih1  = (const float*)d_in[3];
    const float* bhh1  = (const float*)d_in[4];
    const float* Wih2  = (const float*)d_in[5];
    const float* Whh2  = (const float*)d_in[6];
    const float* bih2  = (const float*)d_in[7];
    const float* bhh2  = (const float*)d_in[8];
    const float* fc1_w = (const float*)d_in[9];
    const float* fc1_b = (const float*)d_in[10];
    const float* fc2_w = (const float*)d_in[11];
    const float* fc2_b = (const float*)d_in[12];
    float* out = (float*)d_out;

    const int n_batch = 2048;
    dim3 grid(n_batch / MB), block(BLK);
    lstm_mfma<<<grid, block, 0, stream>>>(x, Wih1, Whh1, bih1, bhh1,
                                          Wih2, Whh2, bih2, bhh2,
                                          fc1_w, fc1_b, fc2_w, fc2_b, out);
}

// Round 17
// 569.692 us; speedup vs baseline: 2.4292x; 1.0783x over previous
//
#include <hip/hip_runtime.h>

// LSTMTrafficPredictor: fused 2-layer LSTM + FC head via MFMA (bf16 hi/lo split).
// B=2048, T=512, IN=4, H1=64, H2=32, FC=16, OUT=1.
// R17 = R14 restored byte-for-byte (575us champion). R16's ACT2 redistribution
// regressed (614us): it inserted an LDS publish->read round-trip INSIDE the
// serial c2 chain and delayed the h2(s-1) write that the next step's MFMA
// needs. Issue-count savings lose when they lengthen the recurrence chain.
// CLOSED AXES (measured):
//  - multi-block/CU overlap: >~80 pinned weight regs/wave forbids >2 waves/SIMD
//    (R10 spill, R15 spill). 1 block x 8 waves is the feasible point.
//  - MFMA count cuts (R12 flat), LDS-read cuts (R13 regressed), ACT2
//    redistribution (R16 regressed). Combined pipe busy ~85%; remaining time
//    is the 512-step serial chain's latency floor.
// Structure: MB=8, BLK=512, grid=256, bounds(512,2), AGPR-pinned frags,
// unroll-2 ping-pong, 1 barrier/step, redistributed ACT1, paired rcp,
// exact-x k-map.
// k-map (K=128): [h1(0..63) | x(64..67) | bias-one(68) | pad | h2(96..127)]
//   L1: 2 tiles/wave (unit w*8+nt*4+quad, acc[rg]=gate rg), ks 0..2
//   L2: 1 tile/wave  (unit w*4+quad,      acc[rg]=gate rg), ks {0,1,3}
//   z offset(k,n) = (k>>5)*512 + (((k>>3)&3)*16+n)*8 + (k&7); frag read = lane*8.
// Redistributed ACT1: lane tl -> unit w*8 + (tl>>5)*4 + ((tl>>3)&3), batch tl&7.

#define T_LEN 512
#define IN_F  4
#define H1    64
#define H2    32
#define FCN   16
#define MB    8
#define BLK   512

typedef __attribute__((ext_vector_type(8))) short s8b;  // 8 bf16 = 4 VGPR
typedef __attribute__((ext_vector_type(4))) float f4;   // MFMA acc
typedef __attribute__((ext_vector_type(4))) int   i4;   // 4 dwords (pin unit)

union S8U { s8b v; i4 d; unsigned short u[8]; };
union F4U { f4 v; i4 d; float f[4]; };

// Pin 4 consecutive regs into AGPRs; asm def kills rematerialization.
#define APIN4(x) asm volatile("" : "+a"((x).d))

__device__ __forceinline__ float rcp_(float x) { return __builtin_amdgcn_rcpf(x); }
__device__ __forceinline__ float tanh_(float x) { return 1.0f - 2.0f * rcp_(__expf(2.0f * x) + 1.0f); }

__device__ __forceinline__ unsigned short bf16_rne(float f) {
    unsigned u = __float_as_uint(f);
    u = u + 0x7FFFu + ((u >> 16) & 1u);
    return (unsigned short)(u >> 16);
}
__device__ __forceinline__ float bf16_f(unsigned short h) {
    return __uint_as_float(((unsigned)h) << 16);
}

// ---- step-body macros (P = read buffer, NP = write buffer, compile-time) ----
#define STEP_MFMA(P)                                                            \
    f4 a1A[2] = {{0,0,0,0},{0,0,0,0}}, a1B[2] = {{0,0,0,0},{0,0,0,0}};          \
    f4 ac2a = bb2.v, ac2b = {0,0,0,0};                                          \
    _Pragma("unroll")                                                           \
    for (int ks = 0; ks < 4; ++ks) {                                            \
        const s8b zh = *(const s8b*)(&zz[P][0][0] + ks * 512 + offF);           \
        const s8b zl = *(const s8b*)(&zz[P][1][0] + ks * 512 + offF);           \
        if (ks < 3) {                                                           \
            _Pragma("unroll")                                                   \
            for (int nt = 0; nt < 2; ++nt) {                                    \
                a1A[nt] = __builtin_amdgcn_mfma_f32_16x16x32_bf16(wf1h[nt][ks].v, zh, a1A[nt], 0, 0, 0); \
                a1B[nt] = __builtin_amdgcn_mfma_f32_16x16x32_bf16(wf1h[nt][ks].v, zl, a1B[nt], 0, 0, 0); \
                a1B[nt] = __builtin_amdgcn_mfma_f32_16x16x32_bf16(wf1l[nt][ks].v, zh, a1B[nt], 0, 0, 0); \
            }                                                                   \
        }                                                                       \
        if (ks != 2) {                                                          \
            const int kf = (ks < 2) ? ks : 2;                                   \
            ac2a = __builtin_amdgcn_mfma_f32_16x16x32_bf16(wf2h[kf].v, zh, ac2a, 0, 0, 0); \
            ac2b = __builtin_amdgcn_mfma_f32_16x16x32_bf16(wf2h[kf].v, zl, ac2b, 0, 0, 0); \
            ac2b = __builtin_amdgcn_mfma_f32_16x16x32_bf16(wf2l[kf].v, zh, ac2b, 0, 0, 0); \
        }                                                                       \
    }

// L1 activations, redistributed: publish summed gates to wave scratch, then
// every lane processes ONE (unit,batch) set. Same-wave LDS -> no barrier.
#define STEP_ACT1(NP)                                                           \
    {                                                                           \
        if (col < MB) {                                                         \
            *(f4*)&gsc[w][quad * 8 + col][0]      = a1A[0] + a1B[0];            \
            *(f4*)&gsc[w][32 + quad * 8 + col][0] = a1A[1] + a1B[1];            \
        }                                                                       \
        const f4 g = *(const f4*)&gsc[w][lane][0];                              \
        const float dI = 1.0f + __expf(-g[0]);                                  \
        const float dF = 1.0f + __expf(-g[1]);                                  \
        const float rIF = rcp_(dI * dF);                                        \
        const float I = dF * rIF, F = dI * rIF;                                 \
        const float dG = __expf(2.0f * g[2]) + 1.0f;                            \
        const float dO = 1.0f + __expf(-g[3]);                                  \
        const float rGO = rcp_(dG * dO);                                        \
        const float G = 1.0f - 2.0f * (dO * rGO), O = dG * rGO;                 \
        c1 = fmaf(F, c1, I * G);                                                \
        const float h = O * tanh_(c1);                                          \
        const unsigned short hh = bf16_rne(h);                                  \
        zz[NP][0][offH] = hh;                                                   \
        zz[NP][1][offH] = bf16_rne(h - bf16_f(hh));                             \
    }

#define STEP_ACT2(NP)                                                           \
    {                                                                           \
        const float dI = 1.0f + __expf(-(ac2a[0] + ac2b[0]));                   \
        const float dF = 1.0f + __expf(-(ac2a[1] + ac2b[1]));                   \
        const float rIF = rcp_(dI * dF);                                        \
        const float I = dF * rIF, F = dI * rIF;                                 \
        const float dG = __expf(2.0f * (ac2a[2] + ac2b[2])) + 1.0f;             \
        const float dO = 1.0f + __expf(-(ac2a[3] + ac2b[3]));                   \
        const float rGO = rcp_(dG * dO);                                        \
        const float G = 1.0f - 2.0f * (dO * rGO), O = dG * rGO;                 \
        c2 = fmaf(F, c2, I * G);                                                \
        const float h = O * tanh_(c2);                                          \
        if (col < MB) {                                                         \
            const unsigned short hh = bf16_rne(h);                              \
            zz[NP][0][off2] = hh;                                               \
            zz[NP][1][off2] = bf16_rne(h - bf16_f(hh));                         \
        }                                                                       \
    }

__global__ __launch_bounds__(BLK, 2)
void lstm_mfma(const float* __restrict__ x,
               const float* __restrict__ Wih1, const float* __restrict__ Whh1,
               const float* __restrict__ bih1, const float* __restrict__ bhh1,
               const float* __restrict__ Wih2, const float* __restrict__ Whh2,
               const float* __restrict__ bih2, const float* __restrict__ bhh2,
               const float* __restrict__ fc1_w, const float* __restrict__ fc1_b,
               const float* __restrict__ fc2_w, const float* __restrict__ fc2_b,
               float* __restrict__ out)
{
    __shared__ __align__(16) unsigned short zz[2][2][2048];  // 16 KB
    __shared__ __align__(16) float gsc[8][64][4];            // 8 KB wave scratch
    __shared__ __align__(16) float h2f[MB * H2];
    __shared__ __align__(16) float fcs[MB * FCN];

    const int t    = threadIdx.x;
    const int lane = t & 63;
    const int w    = t >> 6;      // wave 0..7
    const int col  = lane & 15;   // batch col (valid < MB) / A-frag row
    const int quad = lane >> 4;
    const int b0   = blockIdx.x * MB;

    // ---- weight fragments (gate-complete interleaved mapping) ----
    S8U wf1h[2][3], wf1l[2][3];   // layer1: 2 tiles x ks 0..2
    S8U wf2h[3],    wf2l[3];      // layer2: 1 tile  x ks {0,1,3}
    #pragma unroll
    for (int nt = 0; nt < 2; ++nt) {
        const int r1 = (col & 3) * 64 + w * 8 + nt * 4 + (col >> 2);
        #pragma unroll
        for (int ks = 0; ks < 3; ++ks) {
            #pragma unroll
            for (int j = 0; j < 8; ++j) {
                const int k = ks * 32 + quad * 8 + j;
                float wv;
                if      (k < H1)      wv = Whh1[r1 * H1 + k];
                else if (k < H1 + 4)  wv = Wih1[r1 * IN_F + (k - H1)];
                else if (k == 68)     wv = bih1[r1] + bhh1[r1];   // bias col
                else                  wv = 0.f;
                const unsigned short hh = bf16_rne(wv);
                wf1h[nt][ks].u[j] = hh;
                wf1l[nt][ks].u[j] = bf16_rne(wv - bf16_f(hh));
            }
        }
    }
    {
        const int r2 = (col & 3) * 32 + w * 4 + (col >> 2);
        #pragma unroll
        for (int kf = 0; kf < 3; ++kf) {
            #pragma unroll
            for (int j = 0; j < 8; ++j) {
                const int k = ((kf < 2) ? kf * 32 : 96) + quad * 8 + j;
                const float wv = (k < H1) ? Wih2[r2 * H1 + k]
                                          : Whh2[r2 * H2 + (k - 96)];
                const unsigned short hh = bf16_rne(wv);
                wf2h[kf].u[j] = hh;
                wf2l[kf].u[j] = bf16_rne(wv - bf16_f(hh));
            }
        }
    }
    // layer2 biases as MFMA C-init vector (lane's unit u2 = w*4+quad)
    const int u2 = w * 4 + quad;
    F4U bb2;
    bb2.f[0] = bih2[u2]      + bhh2[u2];
    bb2.f[1] = bih2[32 + u2] + bhh2[32 + u2];
    bb2.f[2] = bih2[64 + u2] + bhh2[64 + u2];
    bb2.f[3] = bih2[96 + u2] + bhh2[96 + u2];

    // ---- PIN fragments + bias into AGPRs ----
    #pragma unroll
    for (int nt = 0; nt < 2; ++nt)
        #pragma unroll
        for (int ks = 0; ks < 3; ++ks) { APIN4(wf1h[nt][ks]); APIN4(wf1l[nt][ks]); }
    #pragma unroll
    for (int kf = 0; kf < 3; ++kf) { APIN4(wf2h[kf]); APIN4(wf2l[kf]); }
    APIN4(bb2);

    // ---- init LDS: zero z; bias-one col (both pp); x(0) ----
    {
        int* pz = (int*)zz;
        #pragma unroll
        for (int i = 0; i < 8; ++i) pz[t + i * BLK] = 0;
    }
    __syncthreads();
    if (t < 16) {                           // off(k=68,n) = 1024 + n*8 + 4
        zz[0][0][1024 + t * 8 + 4] = 0x3F80;
        zz[1][0][1024 + t * 8 + 4] = 0x3F80;
    }
    if (t < MB * IN_F) {                    // x(0) at k=64+f: off = 1024 + n*8 + f
        const int n = t >> 2, f = t & 3;
        const float xv = x[(size_t)(b0 + n) * T_LEN * IN_F + f];
        const unsigned short xh = bf16_rne(xv);
        zz[0][0][1024 + n * 8 + f] = xh;
        zz[0][1][1024 + n * 8 + f] = bf16_rne(xv - bf16_f(xh));
    }
    float c1 = 0.f;   // redistributed: unit w*8+(lane>>5)*4+((lane>>3)&3), batch lane&7
    float c2 = 0.f;   // layer2 unit u2, batch col

    // store offsets
    const int uH   = w * 8 + ((lane >> 5) << 2) + ((lane >> 3) & 3);
    const int nH   = lane & 7;
    const int offH = (uH >> 5) * 512 + (((uH >> 3) & 3) * 16 + nH) * 8 + (uH & 7);
    const int off2 = 1536 + (((u2 >> 3) & 3) * 16 + col) * 8 + (u2 & 7);
    const int offF = lane * 8;                     // frag read base
    const int xn_  = (t >> 2) & 7, xf_ = t & 3;    // x-prefetch role (t < 32)
    const float* xp = x + (size_t)(b0 + xn_) * T_LEN * IN_F + IN_F + xf_;  // -> x(1)
    __syncthreads();

    // ================= main recurrence: unrolled x2, 1 barrier/step ==========
    #pragma unroll 1
    for (int s2 = 0; s2 < T_LEN / 2; ++s2) {
        // ---------- body A: s = 2*s2 (read zz[0], write zz[1]) ----------
        {
            float xn = 0.f;
            if (t < MB * IN_F) xn = *xp;           // x(2*s2+1), always valid
            STEP_MFMA(0)
            STEP_ACT1(1)
            if (s2 != 0) STEP_ACT2(1)              // gates2 belong to step s-1
            if (t < MB * IN_F) {
                const unsigned short xh = bf16_rne(xn);
                zz[1][0][1024 + xn_ * 8 + xf_] = xh;
                zz[1][1][1024 + xn_ * 8 + xf_] = bf16_rne(xn - bf16_f(xh));
            }
            xp += IN_F;
        }
        __syncthreads();
        // ---------- body B: s = 2*s2+1 (read zz[1], write zz[0]) ----------
        {
            float xn = 0.f;
            const bool ld = (t < MB * IN_F) && (s2 != T_LEN / 2 - 1);
            if (ld) xn = *xp;                      // x(2*s2+2)
            STEP_MFMA(1)
            STEP_ACT1(0)
            STEP_ACT2(0)                           // s >= 1 always here
            if (ld) {
                const unsigned short xh = bf16_rne(xn);
                zz[0][0][1024 + xn_ * 8 + xf_] = xh;
                zz[0][1][1024 + xn_ * 8 + xf_] = bf16_rne(xn - bf16_f(xh));
            }
            xp += IN_F;
        }
        __syncthreads();
    }

    // ================= epilogue: layer2 step T-1 (zz[0]: h1(511), h2(510)) ====
    {
        f4 ac2a = bb2.v, ac2b = {0,0,0,0};
        #pragma unroll
        for (int kf = 0; kf < 3; ++kf) {
            const int zks = (kf < 2) ? kf : 3;
            const s8b zh = *(const s8b*)(&zz[0][0][0] + zks * 512 + offF);
            const s8b zl = *(const s8b*)(&zz[0][1][0] + zks * 512 + offF);
            ac2a = __builtin_amdgcn_mfma_f32_16x16x32_bf16(wf2h[kf].v, zh, ac2a, 0, 0, 0);
            ac2b = __builtin_amdgcn_mfma_f32_16x16x32_bf16(wf2h[kf].v, zl, ac2b, 0, 0, 0);
            ac2b = __builtin_amdgcn_mfma_f32_16x16x32_bf16(wf2l[kf].v, zh, ac2b, 0, 0, 0);
        }
        const float dI = 1.0f + __expf(-(ac2a[0] + ac2b[0]));
        const float dF = 1.0f + __expf(-(ac2a[1] + ac2b[1]));
        const float rIF = rcp_(dI * dF);
        const float I = dF * rIF, F = dI * rIF;
        const float dG = __expf(2.0f * (ac2a[2] + ac2b[2])) + 1.0f;
        const float dO = 1.0f + __expf(-(ac2a[3] + ac2b[3]));
        const float rGO = rcp_(dG * dO);
        const float G = 1.0f - 2.0f * (dO * rGO), O = dG * rGO;
        c2 = fmaf(F, c2, I * G);
        if (col < MB) h2f[col * H2 + u2] = O * tanh_(c2);
    }
    __syncthreads();

    // ================= FC head =================
    if (t < MB * FCN) {
        const int b = t >> 4, j = t & 15;
        float s1 = fc1_b[j];
        #pragma unroll
        for (int k = 0; k < H2; ++k)
            s1 = fmaf(fc1_w[j * H2 + k], h2f[b * H2 + k], s1);
        fcs[b * FCN + j] = fmaxf(s1, 0.f);
    }
    __syncthreads();
    if (t < MB) {
        float s2v = fc2_b[0];
        #pragma unroll
        for (int j = 0; j < FCN; ++j)
            s2v = fmaf(fc2_w[j], fcs[t * FCN + j], s2v);
        out[b0 + t] = s2v;
    }
}

extern "C" void kernel_launch(void* const* d_in, const int* in_sizes, int n_in,
                              void* d_out, int out_size, void* d_ws, size_t ws_size,
                              hipStream_t stream) {
    const float* x     = (const float*)d_in[0];
    const float* Wih1  = (const float*)d_in[1];
    const float* Whh1  = (const float*)d_in[2];
    const float* bih1  = (const float*)d_in[3];
    const float* bhh1  = (const float*)d_in[4];
    const float* Wih2  = (const float*)d_in[5];
    const float* Whh2  = (const float*)d_in[6];
    const float* bih2  = (const float*)d_in[7];
    const float* bhh2  = (const float*)d_in[8];
    const float* fc1_w = (const float*)d_in[9];
    const float* fc1_b = (const float*)d_in[10];
    const float* fc2_w = (const float*)d_in[11];
    const float* fc2_b = (const float*)d_in[12];
    float* out = (float*)d_out;

    const int n_batch = 2048;
    dim3 grid(n_batch / MB), block(BLK);
    lstm_mfma<<<grid, block, 0, stream>>>(x, Wih1, Whh1, bih1, bhh1,
                                          Wih2, Whh2, bih2, bhh2,
                                          fc1_w, fc1_b, fc2_w, fc2_b, out);
}